// Round 1
// baseline (18505.638 us; speedup 1.0000x reference)
//
#include <hip/hip_runtime.h>
#include <stdint.h>

typedef unsigned long long u64;

// Monotone float -> uint32 mapping (IEEE total order for non-NaN).
static __device__ __forceinline__ uint32_t f2ord(float f) {
  uint32_t u = __float_as_uint(f);
  return (u & 0x80000000u) ? ~u : (u | 0x80000000u);
}

__global__ void k_zero(float* out, int n) {
  int i = blockIdx.x * blockDim.x + threadIdx.x;
  if (i < n) out[i] = 0.0f;
}

// vals[0..N) = img; vals[N..N+E) = max over edge endpoints
__global__ void k_vals_ve(const float* img, const int* edges, float* vals, int N, int E) {
  int i = blockIdx.x * blockDim.x + threadIdx.x;
  if (i < N) {
    vals[i] = img[i];
  } else if (i < N + E) {
    int e = i - N;
    vals[i] = fmaxf(img[edges[2 * e]], img[edges[2 * e + 1]]);
  }
}

// vals[N+E..m) = max over the 3 edge values of each triangle
__global__ void k_vals_t(const int* tri, float* vals, int N, int E, int F) {
  int i = blockIdx.x * blockDim.x + threadIdx.x;
  if (i < F) {
    float a = vals[N + tri[3 * i]];
    float b = vals[N + tri[3 * i + 1]];
    float c = vals[N + tri[3 * i + 2]];
    vals[N + E + i] = fmaxf(a, fmaxf(b, c));
  }
}

// 64-bit sort keys: (orderable(val) << 32) | idx  — replicates lexsort((dims, vals))
// because dim is monotone in idx. Pad [m, M2) with +inf keys.
__global__ void k_keys(const float* vals, u64* keys, int m, int M2) {
  int i = blockIdx.x * blockDim.x + threadIdx.x;
  if (i < m) keys[i] = ((u64)f2ord(vals[i]) << 32) | (u64)(uint32_t)i;
  else if (i < M2) keys[i] = ~0ull;
}

// Single-block bitonic sort over global memory (M2 power of two).
__global__ void k_sort(u64* keys, int M2) {
  for (int k = 2; k <= M2; k <<= 1) {
    for (int j = k >> 1; j > 0; j >>= 1) {
      for (int i = threadIdx.x; i < M2; i += blockDim.x) {
        int ixj = i ^ j;
        if (ixj > i) {
          u64 a = keys[i], b = keys[ixj];
          bool swap = ((i & k) == 0) ? (a > b) : (a < b);
          if (swap) { keys[i] = b; keys[ixj] = a; }
        }
      }
      __syncthreads();
    }
  }
}

__global__ void k_rank(const u64* keys, const float* vals, int* rank, float* vsorted, int m) {
  int j = blockIdx.x * blockDim.x + threadIdx.x;
  if (j < m) {
    int idx = (int)(keys[j] & 0xffffffffu);
    rank[idx] = j;
    vsorted[j] = vals[idx];
  }
}

// Serial scan over sorted order:
//  - assign each edge its rank among edges (er), build er -> global-rank map
//  - union-find elder rule for dim-0 pairs (writes dgm0)
//  - collect triangles in sorted order (id + value) for the dim-1 reduction
//  - essential dim-0 class: sorted position 0, death = fmax (position m-1)
__global__ void k_scan(const u64* keys, const float* vsorted, const int* edges,
                       const int* rank, int* parent, int* birth,
                       int* er_of_edge, int* er_to_rank,
                       int* tri_id, float* tri_val,
                       float* out, int N, int E, int F, int m) {
  if (threadIdx.x != 0 || blockIdx.x != 0) return;
  for (int v = 0; v < N; ++v) { parent[v] = v; birth[v] = rank[v]; }
  int ec = 0, tc = 0;
  for (int j = 0; j < m; ++j) {
    int idx = (int)(keys[j] & 0xffffffffu);
    if (idx < N) continue;
    if (idx < N + E) {
      int e = idx - N;
      er_of_edge[e] = ec;
      er_to_rank[ec] = j;
      ec++;
      int a = edges[2 * e], b = edges[2 * e + 1];
      int ru = a;
      while (parent[ru] != ru) { int g = parent[parent[ru]]; parent[ru] = g; ru = g; }
      int rv = b;
      while (parent[rv] != rv) { int g = parent[parent[rv]]; parent[rv] = g; rv = g; }
      if (ru != rv) {
        int bu = birth[ru], bv = birth[rv];
        int die = bu > bv ? bu : bv;
        int live = bu < bv ? bu : bv;
        out[2 * die] = vsorted[die];       // birth
        out[2 * die + 1] = vsorted[j];     // death = edge value
        parent[ru] = rv;
        birth[rv] = live;
      }
    } else {
      int t = idx - N - E;
      tri_id[tc] = t;
      tri_val[tc] = vsorted[j];
      tc++;
    }
  }
  // essential dim-0 class: globally eldest simplex = sorted position 0 (a vertex)
  out[0] = vsorted[0];
  out[1] = vsorted[m - 1];  // fmax
}

// Standard left-to-right boundary reduction of the triangle columns, bitset
// over edge-rank space, one 64-lane wave cooperating per column operation.
__global__ void k_reduce(const int* tri_edges, const int* tri_id, const float* tri_val,
                         const int* er_of_edge, const int* er_to_rank, const float* vsorted,
                         u64* colstore, int* pivot_col, float* out1, int E, int F, int W) {
  int lane = threadIdx.x;
  for (int i = lane; i < E; i += 64) pivot_col[i] = -1;
  __syncthreads();
  for (int ts = 0; ts < F; ++ts) {
    u64* col = colstore + (size_t)ts * W;
    for (int w = lane; w < W; w += 64) col[w] = 0;
    __syncthreads();
    if (lane == 0) {
      int t = tri_id[ts];
      #pragma unroll
      for (int k = 0; k < 3; ++k) {
        int er = er_of_edge[tri_edges[3 * t + k]];
        col[er >> 6] |= 1ull << (er & 63);
      }
    }
    __syncthreads();
    // find low = max set bit
    int best = -1;
    for (int w = lane; w < W; w += 64) {
      u64 x = col[w];
      if (x) best = (w << 6) + 63 - __clzll(x);
    }
    for (int off = 32; off; off >>= 1) {
      int o = __shfl_xor(best, off);
      if (o > best) best = o;
    }
    int low = best;
    while (low >= 0 && pivot_col[low] >= 0) {
      const u64* pc = colstore + (size_t)pivot_col[low] * W;
      for (int w = lane; w < W; w += 64) col[w] ^= pc[w];
      __syncthreads();
      best = -1;
      for (int w = lane; w < W; w += 64) {
        u64 x = col[w];
        if (x) best = (w << 6) + 63 - __clzll(x);
      }
      for (int off = 32; off; off >>= 1) {
        int o = __shfl_xor(best, off);
        if (o > best) best = o;
      }
      low = best;
    }
    if (low >= 0 && lane == 0) {
      pivot_col[low] = ts;
      int rb = er_to_rank[low];
      out1[2 * rb] = vsorted[rb];       // birth = positive edge value
      out1[2 * rb + 1] = tri_val[ts];   // death = triangle value
    }
    __syncthreads();
  }
}

extern "C" void kernel_launch(void* const* d_in, const int* in_sizes, int n_in,
                              void* d_out, int out_size, void* d_ws, size_t ws_size,
                              hipStream_t stream) {
  const float* img = (const float*)d_in[0];
  const int* edges = (const int*)d_in[1];
  const int* tri_edges = (const int*)d_in[2];
  int N = in_sizes[0];
  int E = in_sizes[1] / 2;
  int F = in_sizes[2] / 3;
  int m = N + E + F;
  int M2 = 1; while (M2 < m) M2 <<= 1;
  int W = (E + 63) / 64;
  float* out = (float*)d_out;

  char* p = (char*)d_ws;
  auto alloc = [&](size_t bytes) { char* r = p; p += (bytes + 255) & ~(size_t)255; return r; };
  u64* keys       = (u64*)alloc((size_t)M2 * 8);
  float* vals     = (float*)alloc((size_t)m * 4);
  float* vsorted  = (float*)alloc((size_t)m * 4);
  int* rank       = (int*)alloc((size_t)m * 4);
  int* er_of_edge = (int*)alloc((size_t)E * 4);
  int* er_to_rank = (int*)alloc((size_t)E * 4);
  int* parent     = (int*)alloc((size_t)N * 4);
  int* birth      = (int*)alloc((size_t)N * 4);
  int* tri_id     = (int*)alloc((size_t)F * 4);
  float* tri_val  = (float*)alloc((size_t)F * 4);
  int* pivot_col  = (int*)alloc((size_t)E * 4);
  u64* colstore   = (u64*)alloc((size_t)F * (size_t)W * 8);
  (void)ws_size; (void)n_in;

  k_zero<<<(out_size + 255) / 256, 256, 0, stream>>>(out, out_size);
  k_vals_ve<<<(N + E + 255) / 256, 256, 0, stream>>>(img, edges, vals, N, E);
  k_vals_t<<<(F + 255) / 256, 256, 0, stream>>>(tri_edges, vals, N, E, F);
  k_keys<<<(M2 + 255) / 256, 256, 0, stream>>>(vals, keys, m, M2);
  k_sort<<<1, 1024, 0, stream>>>(keys, M2);
  k_rank<<<(m + 255) / 256, 256, 0, stream>>>(keys, vals, rank, vsorted, m);
  k_scan<<<1, 1, 0, stream>>>(keys, vsorted, edges, rank, parent, birth,
                              er_of_edge, er_to_rank, tri_id, tri_val,
                              out, N, E, F, m);
  k_reduce<<<1, 64, 0, stream>>>(tri_edges, tri_id, tri_val,
                                 er_of_edge, er_to_rank, vsorted,
                                 colstore, pivot_col, out + 2 * (size_t)m, E, F, W);
}

// Round 2
// 2881.337 us; speedup vs baseline: 6.4226x; 6.4226x over previous
//
#include <hip/hip_runtime.h>
#include <stdint.h>

typedef unsigned long long u64;

// Problem-size caps (H=W=48 grid per reference).
#define NMAX 2304
#define EMAX 6721
#define FMAX 4418
#define M2C  16384

// Monotone float -> uint32 mapping (IEEE total order for non-NaN).
static __device__ __forceinline__ uint32_t f2ord(float f) {
  uint32_t u = __float_as_uint(f);
  return (u & 0x80000000u) ? ~u : (u | 0x80000000u);
}

__global__ void k_zero(float* out, int n) {
  int i = blockIdx.x * blockDim.x + threadIdx.x;
  if (i < n) out[i] = 0.0f;
}

__global__ void k_zero_i(int* p, int n) {
  int i = blockIdx.x * blockDim.x + threadIdx.x;
  if (i < n) p[i] = 0;
}

// vals[0..N) = img; vals[N..N+E) = max over edge endpoints
__global__ void k_vals_ve(const float* img, const int* edges, float* vals, int N, int E) {
  int i = blockIdx.x * blockDim.x + threadIdx.x;
  if (i < N) {
    vals[i] = img[i];
  } else if (i < N + E) {
    int e = i - N;
    vals[i] = fmaxf(img[edges[2 * e]], img[edges[2 * e + 1]]);
  }
}

// vals[N+E..m) = max over the 3 edge values of each triangle
__global__ void k_vals_t(const int* tri, float* vals, int N, int E, int F) {
  int i = blockIdx.x * blockDim.x + threadIdx.x;
  if (i < F) {
    float a = vals[N + tri[3 * i]];
    float b = vals[N + tri[3 * i + 1]];
    float c = vals[N + tri[3 * i + 2]];
    vals[N + E + i] = fmaxf(a, fmaxf(b, c));
  }
}

// 64-bit sort keys: (orderable(val) << 32) | idx  — replicates lexsort((dims, vals))
// because dim is monotone in original index. Pad [m, M2) with +inf keys.
__global__ void k_keys(const float* vals, u64* keys, int m, int M2) {
  int i = blockIdx.x * blockDim.x + threadIdx.x;
  if (i < m) keys[i] = ((u64)f2ord(vals[i]) << 32) | (u64)(uint32_t)i;
  else if (i < M2) keys[i] = ~0ull;
}

// Single-block bitonic sort fully in LDS (16384 x u64 = 128 KiB).
__global__ __launch_bounds__(1024) void k_sortlds(u64* keys, int M2) {
  __shared__ u64 s[M2C];
  for (int i = threadIdx.x; i < M2; i += 1024) s[i] = keys[i];
  __syncthreads();
  for (int k = 2; k <= M2; k <<= 1) {
    for (int j = k >> 1; j > 0; j >>= 1) {
      for (int i = threadIdx.x; i < M2; i += 1024) {
        int ixj = i ^ j;
        if (ixj > i) {
          u64 a = s[i], b = s[ixj];
          bool up = ((i & k) == 0);
          if (up ? (a > b) : (a < b)) { s[i] = b; s[ixj] = a; }
        }
      }
      __syncthreads();
    }
  }
  for (int i = threadIdx.x; i < M2; i += 1024) keys[i] = s[i];
}

__global__ void k_rank(const u64* keys, const float* vals, int* rank, float* vsorted, int m) {
  int j = blockIdx.x * blockDim.x + threadIdx.x;
  if (j < m) {
    int idx = (int)(keys[j] & 0xffffffffu);
    rank[idx] = j;
    vsorted[j] = vals[idx];
  }
}

// Block-wide scan: assign each edge its rank among edges (er), record er->global
// rank and er->edge-id, in sorted order.
__global__ __launch_bounds__(1024) void k_classify(const u64* keys, int N, int E, int m,
                                                   int* er_to_rank, int* e_of_er) {
  __shared__ int cnt[1024];
  int tid = threadIdx.x;
  int per = (m + 1023) >> 10;
  int lo = tid * per, hi = min(m, lo + per);
  int c = 0;
  for (int j = lo; j < hi; ++j) {
    int idx = (int)(keys[j] & 0xffffffffu);
    c += (idx >= N && idx < N + E);
  }
  cnt[tid] = c;
  __syncthreads();
  for (int off = 1; off < 1024; off <<= 1) {
    int t = (tid >= off) ? cnt[tid - off] : 0;
    __syncthreads();
    cnt[tid] += t;
    __syncthreads();
  }
  int er = cnt[tid] - c;  // exclusive prefix
  for (int j = lo; j < hi; ++j) {
    int idx = (int)(keys[j] & 0xffffffffu);
    if (idx >= N && idx < N + E) {
      er_to_rank[er] = j;
      e_of_er[er] = idx - N;
      er++;
    }
  }
}

// Edge -> adjacent triangles (1 or 2; boundary edges get the outer face later).
__global__ void k_adjfill(const int* tri_edges, int* deg, int* adj, int F3) {
  int i = blockIdx.x * blockDim.x + threadIdx.x;
  if (i < F3) {
    int e = tri_edges[i];
    int t = i / 3;
    int slot = atomicAdd(&deg[e], 1);
    adj[2 * e + slot] = t;
  }
}

// Per sorted-edge dual endpoints: node ids in [0,F] (F = outer face).
__global__ void k_adj_er(const int* e_of_er, const int* deg, const int* adj,
                         int* adjA, int* adjB, int E, int F) {
  int er = blockIdx.x * blockDim.x + threadIdx.x;
  if (er < E) {
    int e = e_of_er[er];
    adjA[er] = adj[2 * e];
    adjB[er] = (deg[e] == 2) ? adj[2 * e + 1] : F;
  }
}

static __device__ __forceinline__ int uf_find(int* par, int x) {
  for (;;) {
    int p = par[x];
    if (p == x) return x;
    int g = par[p];
    par[x] = g;
    x = g;
  }
}

// Two independent serial elder-rule union-finds, all state in LDS.
// Block 0: dim-0 (primal, increasing order). Block 1: dim-1 via dual graph
// (decreasing order; outer node birth = INT_MAX, always elder).
__global__ __launch_bounds__(256) void k_uf(const int* edges, const int* e_of_er,
                                            const int* er_to_rank, const int* rank,
                                            const int* adjA, const int* adjB,
                                            int2* pairs0, int2* pairs1,
                                            int N, int E, int F) {
  __shared__ int sm[3 * EMAX + 2 * (FMAX + 1)];
  int tid = threadIdx.x;
  if (blockIdx.x == 0) {
    int* ea  = sm;
    int* eb  = sm + EMAX;
    int* jr  = sm + 2 * EMAX;
    int* par = sm + 3 * EMAX;
    int* bth = par + NMAX;
    for (int i = tid; i < E; i += 256) {
      int e = e_of_er[i];
      ea[i] = edges[2 * e];
      eb[i] = edges[2 * e + 1];
      jr[i] = er_to_rank[i];
    }
    for (int v = tid; v < N; v += 256) { par[v] = v; bth[v] = rank[v]; }
    __syncthreads();
    if (tid == 0) {
      int c = 0;
      for (int er = 0; er < E; ++er) {
        int ra = uf_find(par, ea[er]);
        int rb = uf_find(par, eb[er]);
        if (ra != rb) {
          int ba = bth[ra], bb = bth[rb];
          int die;
          if (ba < bb) { par[rb] = ra; die = bb; }  // elder ra survives
          else         { par[ra] = rb; die = ba; }
          pairs0[c++] = make_int2(die, jr[er]);
        }
      }
    }
  } else {
    int* ta  = sm;
    int* tb  = sm + EMAX;
    int* jr  = sm + 2 * EMAX;
    int* par = sm + 3 * EMAX;
    int* bth = par + (FMAX + 1);
    for (int i = tid; i < E; i += 256) {
      ta[i] = adjA[i];
      tb[i] = adjB[i];
      jr[i] = er_to_rank[i];
    }
    for (int t = tid; t <= F; t += 256) {
      par[t] = t;
      bth[t] = (t < F) ? rank[N + E + t] : 0x7fffffff;  // outer = eldest in reverse order
    }
    __syncthreads();
    if (tid == 0) {
      int c = 0;
      for (int er = E - 1; er >= 0; --er) {
        int r0 = uf_find(par, ta[er]);
        int r1 = uf_find(par, tb[er]);
        if (r0 != r1) {
          int b0 = bth[r0], b1 = bth[r1];
          int die;
          if (b0 > b1) { par[r1] = r0; die = b1; }  // elder (larger fwd rank) survives
          else         { par[r0] = r1; die = b0; }
          // primal dim-1 pair: birth = this edge's rank, death = dying triangle's rank
          pairs1[c++] = make_int2(jr[er], die);
        }
      }
    }
  }
}

// Materialize diagrams: dgm0 = out[0..2m), dgm1 = out[2m..4m), indexed by rank.
__global__ void k_emit(const int2* pairs0, const int2* pairs1, const float* vs,
                       float* out, int N, int F, int m) {
  int i = blockIdx.x * blockDim.x + threadIdx.x;
  int n0 = N - 1;
  if (i < n0) {
    int2 p = pairs0[i];
    out[2 * p.x] = vs[p.x];
    out[2 * p.x + 1] = vs[p.y];
  } else if (i < n0 + F) {
    int2 p = pairs1[i - n0];
    float* o1 = out + 2 * (size_t)m;
    o1[2 * p.x] = vs[p.x];
    o1[2 * p.x + 1] = vs[p.y];
  } else if (i == n0 + F) {
    // essential dim-0 class: eldest simplex (rank 0), death = fmax (rank m-1)
    out[0] = vs[0];
    out[1] = vs[m - 1];
  }
}

extern "C" void kernel_launch(void* const* d_in, const int* in_sizes, int n_in,
                              void* d_out, int out_size, void* d_ws, size_t ws_size,
                              hipStream_t stream) {
  const float* img = (const float*)d_in[0];
  const int* edges = (const int*)d_in[1];
  const int* tri_edges = (const int*)d_in[2];
  int N = in_sizes[0];
  int E = in_sizes[1] / 2;
  int F = in_sizes[2] / 3;
  int m = N + E + F;
  int M2 = 1; while (M2 < m) M2 <<= 1;
  float* out = (float*)d_out;

  char* p = (char*)d_ws;
  auto alloc = [&](size_t bytes) { char* r = p; p += (bytes + 255) & ~(size_t)255; return r; };
  u64* keys       = (u64*)alloc((size_t)M2 * 8);
  float* vals     = (float*)alloc((size_t)m * 4);
  float* vsorted  = (float*)alloc((size_t)m * 4);
  int* rank       = (int*)alloc((size_t)m * 4);
  int* er_to_rank = (int*)alloc((size_t)E * 4);
  int* e_of_er    = (int*)alloc((size_t)E * 4);
  int* deg        = (int*)alloc((size_t)E * 4);
  int* adj        = (int*)alloc((size_t)E * 8);
  int* adjA       = (int*)alloc((size_t)E * 4);
  int* adjB       = (int*)alloc((size_t)E * 4);
  int2* pairs0    = (int2*)alloc((size_t)N * 8);
  int2* pairs1    = (int2*)alloc((size_t)F * 8);
  (void)ws_size; (void)n_in;

  k_zero<<<(out_size + 255) / 256, 256, 0, stream>>>(out, out_size);
  k_vals_ve<<<(N + E + 255) / 256, 256, 0, stream>>>(img, edges, vals, N, E);
  k_vals_t<<<(F + 255) / 256, 256, 0, stream>>>(tri_edges, vals, N, E, F);
  k_keys<<<(M2 + 255) / 256, 256, 0, stream>>>(vals, keys, m, M2);
  k_sortlds<<<1, 1024, 0, stream>>>(keys, M2);
  k_rank<<<(m + 255) / 256, 256, 0, stream>>>(keys, vals, rank, vsorted, m);
  k_classify<<<1, 1024, 0, stream>>>(keys, N, E, m, er_to_rank, e_of_er);
  k_zero_i<<<(E + 255) / 256, 256, 0, stream>>>(deg, E);
  k_adjfill<<<(3 * F + 255) / 256, 256, 0, stream>>>(tri_edges, deg, adj, 3 * F);
  k_adj_er<<<(E + 255) / 256, 256, 0, stream>>>(e_of_er, deg, adj, adjA, adjB, E, F);
  k_uf<<<2, 256, 0, stream>>>(edges, e_of_er, er_to_rank, rank, adjA, adjB,
                              pairs0, pairs1, N, E, F);
  k_emit<<<(N - 1 + F + 1 + 255) / 256, 256, 0, stream>>>(pairs0, pairs1, vsorted,
                                                          out, N, F, m);
}

// Round 3
// 490.533 us; speedup vs baseline: 37.7255x; 5.8739x over previous
//
#include <hip/hip_runtime.h>
#include <stdint.h>

typedef unsigned long long u64;

// Problem-size caps (H=W=48 grid per reference).
#define NMAX 2304
#define EMAX 6721
#define FMAX 4418
#define M2C  16384
#define KRANGES 64

// Monotone float -> uint32 mapping (IEEE total order for non-NaN).
static __device__ __forceinline__ uint32_t f2ord(float f) {
  uint32_t u = __float_as_uint(f);
  return (u & 0x80000000u) ? ~u : (u | 0x80000000u);
}

__global__ void k_zero(float* out, int n) {
  int i = blockIdx.x * blockDim.x + threadIdx.x;
  if (i < n) out[i] = 0.0f;
}

__global__ void k_zero_i(int* p, int n) {
  int i = blockIdx.x * blockDim.x + threadIdx.x;
  if (i < n) p[i] = 0;
}

// vals[0..N) = img; vals[N..N+E) = max over edge endpoints
__global__ void k_vals_ve(const float* img, const int* edges, float* vals, int N, int E) {
  int i = blockIdx.x * blockDim.x + threadIdx.x;
  if (i < N) {
    vals[i] = img[i];
  } else if (i < N + E) {
    int e = i - N;
    vals[i] = fmaxf(img[edges[2 * e]], img[edges[2 * e + 1]]);
  }
}

// vals[N+E..m) = max over the 3 edge values of each triangle
__global__ void k_vals_t(const int* tri, float* vals, int N, int E, int F) {
  int i = blockIdx.x * blockDim.x + threadIdx.x;
  if (i < F) {
    float a = vals[N + tri[3 * i]];
    float b = vals[N + tri[3 * i + 1]];
    float c = vals[N + tri[3 * i + 2]];
    vals[N + E + i] = fmaxf(a, fmaxf(b, c));
  }
}

// 64-bit sort keys: (orderable(val) << 32) | idx  — replicates lexsort((dims, vals))
// because dim is monotone in original index. Pad [m, M2) with +inf keys.
__global__ void k_keys(const float* vals, u64* keys, int m, int M2) {
  int i = blockIdx.x * blockDim.x + threadIdx.x;
  if (i < m) keys[i] = ((u64)f2ord(vals[i]) << 32) | (u64)(uint32_t)i;
  else if (i < M2) keys[i] = ~0ull;
}

// Single-block bitonic sort fully in LDS (16384 x u64 = 128 KiB).
__global__ __launch_bounds__(1024) void k_sortlds(u64* keys, int M2) {
  __shared__ u64 s[M2C];
  for (int i = threadIdx.x; i < M2; i += 1024) s[i] = keys[i];
  __syncthreads();
  for (int k = 2; k <= M2; k <<= 1) {
    for (int j = k >> 1; j > 0; j >>= 1) {
      for (int i = threadIdx.x; i < M2; i += 1024) {
        int ixj = i ^ j;
        if (ixj > i) {
          u64 a = s[i], b = s[ixj];
          bool up = ((i & k) == 0);
          if (up ? (a > b) : (a < b)) { s[i] = b; s[ixj] = a; }
        }
      }
      __syncthreads();
    }
  }
  for (int i = threadIdx.x; i < M2; i += 1024) keys[i] = s[i];
}

__global__ void k_rank(const u64* keys, const float* vals, float* vsorted, int m) {
  int j = blockIdx.x * blockDim.x + threadIdx.x;
  if (j < m) {
    int idx = (int)(keys[j] & 0xffffffffu);
    vsorted[j] = vals[idx];
  }
}

// Per-class compaction over sorted order: vertex-rank (vr), edge-rank (er),
// triangle-rank (tr) enumerations + forward/backward maps.
__global__ __launch_bounds__(1024) void k_classify(const u64* keys, int N, int E, int F, int m,
                                                   int* vr_to_rank, int* vrank_of_v,
                                                   int* er_to_rank, int* e_of_er,
                                                   int* noderank1, int* trank_of_t) {
  __shared__ int c0[1024], c1[1024], c2[1024];
  int tid = threadIdx.x;
  int per = (m + 1023) >> 10;
  int lo = tid * per, hi = min(m, lo + per);
  int a = 0, b = 0, c = 0;
  for (int j = lo; j < hi; ++j) {
    int idx = (int)(keys[j] & 0xffffffffu);
    if (idx < N) a++;
    else if (idx < N + E) b++;
    else c++;
  }
  c0[tid] = a; c1[tid] = b; c2[tid] = c;
  __syncthreads();
  for (int off = 1; off < 1024; off <<= 1) {
    int t0 = (tid >= off) ? c0[tid - off] : 0;
    int t1 = (tid >= off) ? c1[tid - off] : 0;
    int t2 = (tid >= off) ? c2[tid - off] : 0;
    __syncthreads();
    c0[tid] += t0; c1[tid] += t1; c2[tid] += t2;
    __syncthreads();
  }
  int vr = c0[tid] - a, er = c1[tid] - b, tr = c2[tid] - c;
  for (int j = lo; j < hi; ++j) {
    int idx = (int)(keys[j] & 0xffffffffu);
    if (idx < N) {
      vr_to_rank[vr] = j; vrank_of_v[idx] = vr; vr++;
    } else if (idx < N + E) {
      er_to_rank[er] = j; e_of_er[er] = idx - N; er++;
    } else {
      noderank1[F - tr] = j;           // dual node id = F - trank (outer = 0)
      trank_of_t[idx - N - E] = tr; tr++;
    }
  }
}

// Edge -> adjacent triangles (1 or 2; boundary edges get the outer face).
__global__ void k_adjfill(const int* tri_edges, int* deg, int* adj, int F3) {
  int i = blockIdx.x * blockDim.x + threadIdx.x;
  if (i < F3) {
    int e = tri_edges[i];
    int t = i / 3;
    int slot = atomicAdd(&deg[e], 1);
    adj[2 * e + slot] = t;
  }
}

// Build relabeled edge lists: eAB0[er] = primal endpoints as vranks (dim0);
// eAB1[ehat] = dual endpoints as node ids (dim1, reversed order ehat = E-1-er).
// Node ids: smaller = elder. Outer face = 0.
__global__ void k_build(const int* edges, const int* e_of_er, const int* vrank_of_v,
                        const int* deg, const int* adj, const int* trank_of_t,
                        uint32_t* eAB0, uint32_t* eAB1, int E, int F) {
  int i = blockIdx.x * blockDim.x + threadIdx.x;
  if (i < E) {
    int e = e_of_er[i];
    uint32_t a0 = (uint32_t)vrank_of_v[edges[2 * e]];
    uint32_t b0 = (uint32_t)vrank_of_v[edges[2 * e + 1]];
    eAB0[i] = (a0 << 16) | b0;
    uint32_t na = (uint32_t)(F - trank_of_t[adj[2 * e]]);
    uint32_t nb = (deg[e] == 2) ? (uint32_t)(F - trank_of_t[adj[2 * e + 1]]) : 0u;
    eAB1[E - 1 - i] = (na << 16) | nb;
  }
}

// Range-parallel elder-rule pairing. Block (g, r): graph g (0 = primal/dim0,
// 1 = dual-reversed/dim1), edge range [r*C, (r+1)*C). Phase A: prefix-graph
// connected components via monotone atomicMin label propagation + pointer
// jumping in LDS (fixpoint = per-component min node id = component birth).
// Phase B: one thread runs serial UF over the range's edges from those labels.
__global__ __launch_bounds__(512) void k_pair(const uint32_t* eAB0, const uint32_t* eAB1,
                                              int2* pairs0, int2* pairs1, int* cntg,
                                              int N, int E, int F, int C) {
  __shared__ uint32_t s_eab[EMAX];
  __shared__ int s_lab[FMAX + 1];
  __shared__ int s_par[FMAX + 1];
  __shared__ int s_ch;
  int tid = threadIdx.x;
  int g = blockIdx.x / KRANGES;
  int r = blockIdx.x % KRANGES;
  int NODES = (g == 0) ? N : (F + 1);
  const uint32_t* eAB = (g == 0) ? eAB0 : eAB1;
  int P = r * C;
  if (P >= E) { if (tid == 0) cntg[blockIdx.x] = 0; return; }
  int hi = min(P + C, E);
  for (int i = tid; i < hi; i += 512) s_eab[i] = eAB[i];
  for (int x = tid; x < NODES; x += 512) { s_lab[x] = x; s_par[x] = x; }
  __syncthreads();
  if (r > 0) {
    for (;;) {
      if (tid == 0) s_ch = 0;
      __syncthreads();
      int ch = 0;
      for (int i = tid; i < P; i += 512) {
        uint32_t ab = s_eab[i];
        int a = (int)(ab >> 16), b = (int)(ab & 0xffffu);
        int la = s_lab[a], lb = s_lab[b];
        if (la != lb) {
          int mn = min(la, lb);
          if (la > mn) { atomicMin(&s_lab[a], mn); ch = 1; }
          if (lb > mn) { atomicMin(&s_lab[b], mn); ch = 1; }
        }
      }
      if (ch) s_ch = 1;
      __syncthreads();
      if (!s_ch) break;
      for (int x = tid; x < NODES; x += 512) {
        int v = s_lab[x]; int w = s_lab[v];
        if (w < v) atomicMin(&s_lab[x], w);
      }
      __syncthreads();
      for (int x = tid; x < NODES; x += 512) {
        int v = s_lab[x]; int w = s_lab[v];
        if (w < v) atomicMin(&s_lab[x], w);
      }
      __syncthreads();
    }
  }
  if (tid == 0) {
    int2* pr = (g == 0) ? pairs0 : pairs1;
    int base = r * C, c = 0;
    for (int i = P; i < hi; ++i) {
      uint32_t ab = s_eab[i];
      int a = (int)(ab >> 16), b = (int)(ab & 0xffffu);
      int x = s_lab[a];
      while (s_par[x] != x) { s_par[x] = s_par[s_par[x]]; x = s_par[x]; }
      int y = s_lab[b];
      while (s_par[y] != y) { s_par[y] = s_par[s_par[y]]; y = s_par[y]; }
      if (x != y) {
        int die = x > y ? x : y, sur = x < y ? x : y;
        s_par[die] = sur;
        pr[base + c] = make_int2(die, i);
        c++;
      }
    }
    cntg[blockIdx.x] = c;
  }
}

// Materialize diagrams from pair records. dgm0 = out[0..2m), dgm1 = out[2m..4m).
__global__ void k_emit(const int2* pairs0, const int2* pairs1, const int* cntg,
                       const int* vr_to_rank, const int* er_to_rank, const int* noderank1,
                       const float* vs, float* out, int E, int C, int m) {
  int i = blockIdx.x * blockDim.x + threadIdx.x;
  int tot = KRANGES * C;
  if (i < tot) {
    int r = i / C, q = i % C;
    if (q < cntg[r]) {
      int2 p = pairs0[i];
      int b = vr_to_rank[p.x], d = er_to_rank[p.y];
      out[2 * b] = vs[b];
      out[2 * b + 1] = vs[d];
    }
  } else if (i < 2 * tot) {
    int ii = i - tot;
    int r = ii / C, q = ii % C;
    if (q < cntg[KRANGES + r]) {
      int2 p = pairs1[ii];
      int er = E - 1 - p.y;
      int b = er_to_rank[er], d = noderank1[p.x];
      float* o1 = out + 2 * (size_t)m;
      o1[2 * b] = vs[b];
      o1[2 * b + 1] = vs[d];
    }
  } else if (i == 2 * tot) {
    // essential dim-0 class: eldest simplex (rank 0), death = fmax (rank m-1)
    out[0] = vs[0];
    out[1] = vs[m - 1];
  }
}

extern "C" void kernel_launch(void* const* d_in, const int* in_sizes, int n_in,
                              void* d_out, int out_size, void* d_ws, size_t ws_size,
                              hipStream_t stream) {
  const float* img = (const float*)d_in[0];
  const int* edges = (const int*)d_in[1];
  const int* tri_edges = (const int*)d_in[2];
  int N = in_sizes[0];
  int E = in_sizes[1] / 2;
  int F = in_sizes[2] / 3;
  int m = N + E + F;
  int M2 = 1; while (M2 < m) M2 <<= 1;
  int C = (E + KRANGES - 1) / KRANGES;
  float* out = (float*)d_out;

  char* p = (char*)d_ws;
  auto alloc = [&](size_t bytes) { char* r = p; p += (bytes + 255) & ~(size_t)255; return r; };
  u64* keys        = (u64*)alloc((size_t)M2 * 8);
  float* vals      = (float*)alloc((size_t)m * 4);
  float* vsorted   = (float*)alloc((size_t)m * 4);
  int* vr_to_rank  = (int*)alloc((size_t)N * 4);
  int* vrank_of_v  = (int*)alloc((size_t)N * 4);
  int* er_to_rank  = (int*)alloc((size_t)E * 4);
  int* e_of_er     = (int*)alloc((size_t)E * 4);
  int* noderank1   = (int*)alloc((size_t)(F + 1) * 4);
  int* trank_of_t  = (int*)alloc((size_t)F * 4);
  int* deg         = (int*)alloc((size_t)E * 4);
  int* adj         = (int*)alloc((size_t)E * 8);
  uint32_t* eAB0   = (uint32_t*)alloc((size_t)E * 4);
  uint32_t* eAB1   = (uint32_t*)alloc((size_t)E * 4);
  int2* pairs0     = (int2*)alloc((size_t)KRANGES * C * 8);
  int2* pairs1     = (int2*)alloc((size_t)KRANGES * C * 8);
  int* cntg        = (int*)alloc((size_t)2 * KRANGES * 4);
  (void)ws_size; (void)n_in;

  k_zero<<<(out_size + 255) / 256, 256, 0, stream>>>(out, out_size);
  k_vals_ve<<<(N + E + 255) / 256, 256, 0, stream>>>(img, edges, vals, N, E);
  k_vals_t<<<(F + 255) / 256, 256, 0, stream>>>(tri_edges, vals, N, E, F);
  k_keys<<<(M2 + 255) / 256, 256, 0, stream>>>(vals, keys, m, M2);
  k_sortlds<<<1, 1024, 0, stream>>>(keys, M2);
  k_rank<<<(m + 255) / 256, 256, 0, stream>>>(keys, vals, vsorted, m);
  k_classify<<<1, 1024, 0, stream>>>(keys, N, E, F, m, vr_to_rank, vrank_of_v,
                                     er_to_rank, e_of_er, noderank1, trank_of_t);
  k_zero_i<<<(E + 255) / 256, 256, 0, stream>>>(deg, E);
  k_adjfill<<<(3 * F + 255) / 256, 256, 0, stream>>>(tri_edges, deg, adj, 3 * F);
  k_build<<<(E + 255) / 256, 256, 0, stream>>>(edges, e_of_er, vrank_of_v,
                                               deg, adj, trank_of_t, eAB0, eAB1, E, F);
  k_pair<<<2 * KRANGES, 512, 0, stream>>>(eAB0, eAB1, pairs0, pairs1, cntg, N, E, F, C);
  k_emit<<<(2 * KRANGES * C + 1 + 255) / 256, 256, 0, stream>>>(pairs0, pairs1, cntg,
                                                                vr_to_rank, er_to_rank,
                                                                noderank1, vsorted, out,
                                                                E, C, m);
}

// Round 4
// 264.714 us; speedup vs baseline: 69.9082x; 1.8531x over previous
//
#include <hip/hip_runtime.h>
#include <stdint.h>

typedef unsigned long long u64;

// Problem-size caps (H=W=48 grid per reference).
#define NMAX 2304
#define EMAX 6721
#define FMAX 4418
#define KRANGES 64
#define TS 2048

// Monotone float -> uint32 mapping (IEEE total order for non-NaN).
static __device__ __forceinline__ uint32_t f2ord(float f) {
  uint32_t u = __float_as_uint(f);
  return (u & 0x80000000u) ? ~u : (u | 0x80000000u);
}

// Zero the two atomic-accumulator arrays (pack: m u32, deg: E u32).
__global__ void k_zero2(uint32_t* pack, int m, int* deg, int E) {
  int i = blockIdx.x * blockDim.x + threadIdx.x;
  if (i < m) pack[i] = 0u;
  if (i < E) deg[i] = 0;
}

// Fused prep: zero output, compute all simplex values directly from img,
// build sort keys, and fill edge->triangle adjacency (atomics).
__global__ void k_prep(const float* img, const int* edges, const int* tri_edges,
                       float* vals, u64* keys, int* deg, int* adj, float* out,
                       int N, int E, int F, int m, int out_n) {
  int i = blockIdx.x * blockDim.x + threadIdx.x;
  if (i < out_n) out[i] = 0.0f;
  if (i < m) {
    float v;
    if (i < N) {
      v = img[i];
    } else if (i < N + E) {
      int e = i - N;
      v = fmaxf(img[edges[2 * e]], img[edges[2 * e + 1]]);
    } else {
      int t = i - N - E;
      float mx = -3.402823466e38f;
      #pragma unroll
      for (int k = 0; k < 3; ++k) {
        int e = tri_edges[3 * t + k];
        mx = fmaxf(mx, fmaxf(img[edges[2 * e]], img[edges[2 * e + 1]]));
      }
      v = mx;
    }
    vals[i] = v;
    keys[i] = ((u64)f2ord(v) << 32) | (u64)(uint32_t)i;
  }
  if (i < 3 * F) {
    int e = tri_edges[i];
    int t = i / 3;
    int slot = atomicAdd(&deg[e], 1);
    adj[2 * e + slot] = t;
  }
}

// Counting-rank: grid (tile, key-block). Each block stages one TS-key tile in
// LDS; each thread counts {tile keys < its key} (total + same-class, classes
// segmented by position since simplex classes are contiguous index ranges).
// One packed atomicAdd per (key, tile).
__global__ __launch_bounds__(256) void k_count(const u64* keys, uint32_t* pack,
                                               int N, int E, int m) {
  __shared__ u64 s[TS];
  int base = blockIdx.x * TS;
  int lim = min(TS, m - base);
  for (int j = threadIdx.x; j < lim; j += 256) s[j] = keys[base + j];
  __syncthreads();
  int ki = blockIdx.y * 256 + threadIdx.x;
  if (ki >= m) return;
  u64 mykey = keys[ki];
  int myclass = (ki < N) ? 0 : (ki < N + E ? 1 : 2);
  int end = base + lim;
  int e0 = min(end, N);
  int b1 = max(base, N), e1 = min(end, N + E);
  int b2 = max(base, N + E);
  int c0 = 0, c1 = 0, c2 = 0;
  for (int j = base; j < e0; ++j) c0 += (s[j - base] < mykey);
  for (int j = b1; j < e1; ++j) c1 += (s[j - base] < mykey);
  for (int j = b2; j < end; ++j) c2 += (s[j - base] < mykey);
  uint32_t tot = (uint32_t)(c0 + c1 + c2);
  uint32_t cls = (uint32_t)(myclass == 0 ? c0 : (myclass == 1 ? c1 : c2));
  atomicAdd(&pack[ki], (cls << 16) | tot);
}

// Scatter: unpack ranks, build vsorted + all class-rank maps in parallel.
__global__ void k_scatter(const uint32_t* pack, const float* vals,
                          float* vsorted, int* vr_to_rank, int* vrank_of_v,
                          int* er_to_rank, int* e_of_er, int* noderank1, int* trank_of_t,
                          int N, int E, int F, int m) {
  int i = blockIdx.x * blockDim.x + threadIdx.x;
  if (i >= m) return;
  uint32_t pk = pack[i];
  int rank = (int)(pk & 0xffffu);
  int cls = (int)(pk >> 16);
  vsorted[rank] = vals[i];
  if (i < N) {
    vr_to_rank[cls] = rank;
    vrank_of_v[i] = cls;
  } else if (i < N + E) {
    er_to_rank[cls] = rank;
    e_of_er[cls] = i - N;
  } else {
    noderank1[F - cls] = rank;   // dual node id = F - trank (outer = 0)
    trank_of_t[i - N - E] = cls;
  }
}

// Build relabeled edge lists: eAB0[er] = primal endpoints as vranks (dim0);
// eAB1[ehat] = dual endpoints as node ids (dim1, reversed order ehat = E-1-er).
// Node ids: smaller = elder. Outer face = 0.
__global__ void k_build(const int* edges, const int* e_of_er, const int* vrank_of_v,
                        const int* deg, const int* adj, const int* trank_of_t,
                        uint32_t* eAB0, uint32_t* eAB1, int E, int F) {
  int i = blockIdx.x * blockDim.x + threadIdx.x;
  if (i < E) {
    int e = e_of_er[i];
    uint32_t a0 = (uint32_t)vrank_of_v[edges[2 * e]];
    uint32_t b0 = (uint32_t)vrank_of_v[edges[2 * e + 1]];
    eAB0[i] = (a0 << 16) | b0;
    uint32_t na = (uint32_t)(F - trank_of_t[adj[2 * e]]);
    uint32_t nb = (deg[e] == 2) ? (uint32_t)(F - trank_of_t[adj[2 * e + 1]]) : 0u;
    eAB1[E - 1 - i] = (na << 16) | nb;
  }
}

// Range-parallel elder-rule pairing. Block (g, r): graph g (0 = primal/dim0,
// 1 = dual-reversed/dim1), edge range [r*C, (r+1)*C). Phase A: prefix-graph
// connected components via monotone atomicMin label propagation + pointer
// jumping in LDS (fixpoint = per-component min node id = component birth).
// Phase B: one thread runs serial UF over the range's edges from those labels.
__global__ __launch_bounds__(512) void k_pair(const uint32_t* eAB0, const uint32_t* eAB1,
                                              int2* pairs0, int2* pairs1, int* cntg,
                                              int N, int E, int F, int C) {
  __shared__ uint32_t s_eab[EMAX];
  __shared__ int s_lab[FMAX + 1];
  __shared__ int s_par[FMAX + 1];
  __shared__ int s_ch;
  int tid = threadIdx.x;
  int g = blockIdx.x / KRANGES;
  int r = blockIdx.x % KRANGES;
  int NODES = (g == 0) ? N : (F + 1);
  const uint32_t* eAB = (g == 0) ? eAB0 : eAB1;
  int P = r * C;
  if (P >= E) { if (tid == 0) cntg[blockIdx.x] = 0; return; }
  int hi = min(P + C, E);
  for (int i = tid; i < hi; i += 512) s_eab[i] = eAB[i];
  for (int x = tid; x < NODES; x += 512) { s_lab[x] = x; s_par[x] = x; }
  __syncthreads();
  if (r > 0) {
    for (;;) {
      if (tid == 0) s_ch = 0;
      __syncthreads();
      int ch = 0;
      for (int i = tid; i < P; i += 512) {
        uint32_t ab = s_eab[i];
        int a = (int)(ab >> 16), b = (int)(ab & 0xffffu);
        int la = s_lab[a], lb = s_lab[b];
        if (la != lb) {
          int mn = min(la, lb);
          if (la > mn) { atomicMin(&s_lab[a], mn); ch = 1; }
          if (lb > mn) { atomicMin(&s_lab[b], mn); ch = 1; }
        }
      }
      if (ch) s_ch = 1;
      __syncthreads();
      if (!s_ch) break;
      for (int x = tid; x < NODES; x += 512) {
        int v = s_lab[x]; int w = s_lab[v];
        if (w < v) atomicMin(&s_lab[x], w);
      }
      __syncthreads();
      for (int x = tid; x < NODES; x += 512) {
        int v = s_lab[x]; int w = s_lab[v];
        if (w < v) atomicMin(&s_lab[x], w);
      }
      __syncthreads();
    }
  }
  if (tid == 0) {
    int2* pr = (g == 0) ? pairs0 : pairs1;
    int base = r * C, c = 0;
    for (int i = P; i < hi; ++i) {
      uint32_t ab = s_eab[i];
      int a = (int)(ab >> 16), b = (int)(ab & 0xffffu);
      int x = s_lab[a];
      while (s_par[x] != x) { s_par[x] = s_par[s_par[x]]; x = s_par[x]; }
      int y = s_lab[b];
      while (s_par[y] != y) { s_par[y] = s_par[s_par[y]]; y = s_par[y]; }
      if (x != y) {
        int die = x > y ? x : y, sur = x < y ? x : y;
        s_par[die] = sur;
        pr[base + c] = make_int2(die, i);
        c++;
      }
    }
    cntg[blockIdx.x] = c;
  }
}

// Materialize diagrams from pair records. dgm0 = out[0..2m), dgm1 = out[2m..4m).
__global__ void k_emit(const int2* pairs0, const int2* pairs1, const int* cntg,
                       const int* vr_to_rank, const int* er_to_rank, const int* noderank1,
                       const float* vs, float* out, int E, int C, int m) {
  int i = blockIdx.x * blockDim.x + threadIdx.x;
  int tot = KRANGES * C;
  if (i < tot) {
    int r = i / C, q = i % C;
    if (q < cntg[r]) {
      int2 p = pairs0[i];
      int b = vr_to_rank[p.x], d = er_to_rank[p.y];
      out[2 * b] = vs[b];
      out[2 * b + 1] = vs[d];
    }
  } else if (i < 2 * tot) {
    int ii = i - tot;
    int r = ii / C, q = ii % C;
    if (q < cntg[KRANGES + r]) {
      int2 p = pairs1[ii];
      int er = E - 1 - p.y;
      int b = er_to_rank[er], d = noderank1[p.x];
      float* o1 = out + 2 * (size_t)m;
      o1[2 * b] = vs[b];
      o1[2 * b + 1] = vs[d];
    }
  } else if (i == 2 * tot) {
    // essential dim-0 class: eldest simplex (rank 0), death = fmax (rank m-1)
    out[0] = vs[0];
    out[1] = vs[m - 1];
  }
}

extern "C" void kernel_launch(void* const* d_in, const int* in_sizes, int n_in,
                              void* d_out, int out_size, void* d_ws, size_t ws_size,
                              hipStream_t stream) {
  const float* img = (const float*)d_in[0];
  const int* edges = (const int*)d_in[1];
  const int* tri_edges = (const int*)d_in[2];
  int N = in_sizes[0];
  int E = in_sizes[1] / 2;
  int F = in_sizes[2] / 3;
  int m = N + E + F;
  int C = (E + KRANGES - 1) / KRANGES;
  int NT = (m + TS - 1) / TS;
  int KB = (m + 255) / 256;
  float* out = (float*)d_out;

  char* p = (char*)d_ws;
  auto alloc = [&](size_t bytes) { char* r = p; p += (bytes + 255) & ~(size_t)255; return r; };
  u64* keys        = (u64*)alloc((size_t)m * 8);
  float* vals      = (float*)alloc((size_t)m * 4);
  float* vsorted   = (float*)alloc((size_t)m * 4);
  uint32_t* pack   = (uint32_t*)alloc((size_t)m * 4);
  int* vr_to_rank  = (int*)alloc((size_t)N * 4);
  int* vrank_of_v  = (int*)alloc((size_t)N * 4);
  int* er_to_rank  = (int*)alloc((size_t)E * 4);
  int* e_of_er     = (int*)alloc((size_t)E * 4);
  int* noderank1   = (int*)alloc((size_t)(F + 1) * 4);
  int* trank_of_t  = (int*)alloc((size_t)F * 4);
  int* deg         = (int*)alloc((size_t)E * 4);
  int* adj         = (int*)alloc((size_t)E * 8);
  uint32_t* eAB0   = (uint32_t*)alloc((size_t)E * 4);
  uint32_t* eAB1   = (uint32_t*)alloc((size_t)E * 4);
  int2* pairs0     = (int2*)alloc((size_t)KRANGES * C * 8);
  int2* pairs1     = (int2*)alloc((size_t)KRANGES * C * 8);
  int* cntg        = (int*)alloc((size_t)2 * KRANGES * 4);
  (void)ws_size; (void)n_in;

  int out_n = out_size;
  int prep_n = out_n > m ? out_n : m;
  if (prep_n < 3 * F) prep_n = 3 * F;

  k_zero2<<<(m + 255) / 256, 256, 0, stream>>>(pack, m, deg, E);
  k_prep<<<(prep_n + 255) / 256, 256, 0, stream>>>(img, edges, tri_edges, vals, keys,
                                                   deg, adj, out, N, E, F, m, out_n);
  dim3 cg(NT, KB);
  k_count<<<cg, 256, 0, stream>>>(keys, pack, N, E, m);
  k_scatter<<<(m + 255) / 256, 256, 0, stream>>>(pack, vals, vsorted,
                                                 vr_to_rank, vrank_of_v,
                                                 er_to_rank, e_of_er,
                                                 noderank1, trank_of_t, N, E, F, m);
  k_build<<<(E + 255) / 256, 256, 0, stream>>>(edges, e_of_er, vrank_of_v,
                                               deg, adj, trank_of_t, eAB0, eAB1, E, F);
  k_pair<<<2 * KRANGES, 512, 0, stream>>>(eAB0, eAB1, pairs0, pairs1, cntg, N, E, F, C);
  k_emit<<<(2 * KRANGES * C + 1 + 255) / 256, 256, 0, stream>>>(pairs0, pairs1, cntg,
                                                                vr_to_rank, er_to_rank,
                                                                noderank1, vsorted, out,
                                                                E, C, m);
}

// Round 5
// 196.556 us; speedup vs baseline: 94.1495x; 1.3468x over previous
//
#include <hip/hip_runtime.h>
#include <stdint.h>

typedef unsigned long long u64;

// Problem-size caps (H=W=48 grid per reference).
#define NMAX 2304
#define EMAX 6721
#define FMAX 4418
#define KRANGES 128
#define CMAX 256
#define TS 2048

// Monotone float -> uint32 mapping (IEEE total order for non-NaN).
static __device__ __forceinline__ uint32_t f2ord(float f) {
  uint32_t u = __float_as_uint(f);
  return (u & 0x80000000u) ? ~u : (u | 0x80000000u);
}

// Fused prep: zero output, compute all simplex values directly from img,
// build sort keys, and fill edge->triangle adjacency (atomics; deg pre-zeroed).
__global__ void k_prep(const float* img, const int* edges, const int* tri_edges,
                       float* vals, u64* keys, int* deg, int* adj, float* out,
                       int N, int E, int F, int m, int out_n) {
  int i = blockIdx.x * blockDim.x + threadIdx.x;
  if (i < out_n) out[i] = 0.0f;
  if (i < m) {
    float v;
    if (i < N) {
      v = img[i];
    } else if (i < N + E) {
      int e = i - N;
      v = fmaxf(img[edges[2 * e]], img[edges[2 * e + 1]]);
    } else {
      int t = i - N - E;
      float mx = -3.402823466e38f;
      #pragma unroll
      for (int k = 0; k < 3; ++k) {
        int e = tri_edges[3 * t + k];
        mx = fmaxf(mx, fmaxf(img[edges[2 * e]], img[edges[2 * e + 1]]));
      }
      v = mx;
    }
    vals[i] = v;
    keys[i] = ((u64)f2ord(v) << 32) | (u64)(uint32_t)i;
  }
  if (i < 3 * F) {
    int e = tri_edges[i];
    int t = i / 3;
    int slot = atomicAdd(&deg[e], 1);
    adj[2 * e + slot] = t;
  }
}

// Counting-rank, 4 keys/thread: each block stages one TS-key tile in LDS; each
// thread counts {tile keys < key} for 4 keys (class-segmented by position since
// classes are contiguous index ranges). One packed atomicAdd per (key, tile).
__global__ __launch_bounds__(256) void k_count(const u64* keys, uint32_t* pack,
                                               int N, int E, int m) {
  __shared__ u64 s[TS];
  int base = blockIdx.x * TS;
  int lim = min(TS, m - base);
  for (int j = threadIdx.x; j < lim; j += 256) s[j] = keys[base + j];
  __syncthreads();
  int ki[4]; bool ok[4]; u64 key[4]; int cls[4];
  #pragma unroll
  for (int k = 0; k < 4; ++k) {
    ki[k] = blockIdx.y * 1024 + k * 256 + threadIdx.x;
    ok[k] = ki[k] < m;
    key[k] = ok[k] ? keys[ki[k]] : ~0ull;
    cls[k] = (ki[k] < N) ? 0 : (ki[k] < N + E ? 1 : 2);
  }
  int s1 = min(max(N - base, 0), lim);
  int s2 = min(max(N + E - base, 0), lim);
  int ktot[4] = {0, 0, 0, 0}, kcls[4] = {0, 0, 0, 0};
  int segb[4] = {0, s1, s2, lim};
  #pragma unroll
  for (int seg = 0; seg < 3; ++seg) {
    int tmp[4] = {0, 0, 0, 0};
    for (int j = segb[seg]; j < segb[seg + 1]; ++j) {
      u64 sj = s[j];
      #pragma unroll
      for (int k = 0; k < 4; ++k) tmp[k] += (sj < key[k]);
    }
    #pragma unroll
    for (int k = 0; k < 4; ++k) {
      ktot[k] += tmp[k];
      if (cls[k] == seg) kcls[k] += tmp[k];
    }
  }
  #pragma unroll
  for (int k = 0; k < 4; ++k)
    if (ok[k]) atomicAdd(&pack[ki[k]], ((uint32_t)kcls[k] << 16) | (uint32_t)ktot[k]);
}

// Fused scatter+build: everything read straight out of pack[].
// eAB0[er] = primal endpoints as vranks; eAB1[E-1-er] = dual endpoints as node
// ids (node id = F - trank; outer face = 0; smaller = elder).
__global__ void k_maps(const uint32_t* pack, const float* vals, const int* edges,
                       const int* deg, const int* adj,
                       float* vsorted, int* vr_to_rank, int* er_to_rank, int* noderank1,
                       uint32_t* eAB0, uint32_t* eAB1,
                       int N, int E, int F, int m) {
  int i = blockIdx.x * blockDim.x + threadIdx.x;
  if (i >= m) return;
  uint32_t pk = pack[i];
  int rank = (int)(pk & 0xffffu);
  int cls = (int)(pk >> 16);
  vsorted[rank] = vals[i];
  if (i < N) {
    vr_to_rank[cls] = rank;
  } else if (i < N + E) {
    int e = i - N, er = cls;
    er_to_rank[er] = rank;
    uint32_t va = pack[edges[2 * e]] >> 16;
    uint32_t vb = pack[edges[2 * e + 1]] >> 16;
    eAB0[er] = (va << 16) | vb;
    uint32_t na = (uint32_t)F - (pack[N + E + adj[2 * e]] >> 16);
    uint32_t nb = (deg[e] == 2) ? ((uint32_t)F - (pack[N + E + adj[2 * e + 1]] >> 16)) : 0u;
    eAB1[E - 1 - er] = (na << 16) | nb;
  } else {
    noderank1[F - cls] = rank;
  }
}

// ECL-CC representative with inline path compression (benign races; final
// root of every component = its minimum node id — deterministic).
static __device__ __forceinline__ int rep(volatile int* par, int v) {
  int p = par[v];
  if (p == v) return v;
  int gp = par[p];
  while (p != gp) {
    par[v] = gp;
    v = p; p = gp; gp = par[p];
  }
  return p;
}

// Range-parallel elder-rule pairing. Block (g, r): graph g (0 = primal/dim0,
// 1 = dual-reversed/dim1), edge range [P, P+C). Phase A: prefix-graph DSU via
// asynchronous min-hooking (each prefix edge processed ONCE, atomicCAS hooks
// larger root under smaller) + full compression. Phase B: one thread runs the
// serial elder-rule UF over the range's edges (root id = component birth).
__global__ __launch_bounds__(512) void k_pair(const uint32_t* eAB0, const uint32_t* eAB1,
                                              int2* pairs0, int2* pairs1, int* cntg,
                                              int N, int E, int F, int C) {
  __shared__ int s_par[FMAX + 1];
  __shared__ uint32_t s_re[CMAX];
  volatile int* vp = s_par;
  int tid = threadIdx.x;
  int g = blockIdx.x / KRANGES;
  int r = blockIdx.x % KRANGES;
  int NODES = (g == 0) ? N : (F + 1);
  const uint32_t* eAB = (g == 0) ? eAB0 : eAB1;
  int P = r * C;
  if (P >= E) { if (tid == 0) cntg[blockIdx.x] = 0; return; }
  int hi = min(P + C, E);
  for (int x = tid; x < NODES; x += 512) s_par[x] = x;
  for (int q = tid; q < hi - P; q += 512) s_re[q] = eAB[P + q];
  __syncthreads();
  // Phase A: async hooking over prefix edges [0, P)
  for (int i = tid; i < P; i += 512) {
    uint32_t ab = eAB[i];
    int a = (int)(ab >> 16), b = (int)(ab & 0xffffu);
    int u = rep(vp, a), w = rep(vp, b);
    while (u != w) {
      if (u < w) { int t = u; u = w; w = t; }
      int old = atomicCAS((int*)&s_par[u], u, w);
      if (old == u) break;
      u = rep(vp, old);
      w = rep(vp, w);
    }
  }
  __syncthreads();
  // Full compression: par[x] = root(x) (= component min)
  for (int x = tid; x < NODES; x += 512) {
    int r0 = x;
    while (vp[r0] != r0) r0 = vp[r0];
    s_par[x] = r0;
  }
  __syncthreads();
  // Phase B: serial elder-rule UF over range edges
  if (tid == 0) {
    int2* pr = (g == 0) ? pairs0 : pairs1;
    int base = r * C, c = 0;
    for (int q = 0; q < hi - P; ++q) {
      uint32_t ab = s_re[q];
      int a = (int)(ab >> 16), b = (int)(ab & 0xffffu);
      int x = a;
      while (s_par[x] != x) { s_par[x] = s_par[s_par[x]]; x = s_par[x]; }
      int y = b;
      while (s_par[y] != y) { s_par[y] = s_par[s_par[y]]; y = s_par[y]; }
      if (x != y) {
        int die = x > y ? x : y, sur = x < y ? x : y;
        s_par[die] = sur;
        pr[base + c] = make_int2(die, P + q);
        c++;
      }
    }
    cntg[blockIdx.x] = c;
  }
}

// Materialize diagrams from pair records. dgm0 = out[0..2m), dgm1 = out[2m..4m).
__global__ void k_emit(const int2* pairs0, const int2* pairs1, const int* cntg,
                       const int* vr_to_rank, const int* er_to_rank, const int* noderank1,
                       const float* vs, float* out, int E, int C, int m) {
  int i = blockIdx.x * blockDim.x + threadIdx.x;
  int tot = KRANGES * C;
  if (i < tot) {
    int r = i / C, q = i % C;
    if (q < cntg[r]) {
      int2 p = pairs0[i];
      int b = vr_to_rank[p.x], d = er_to_rank[p.y];
      out[2 * b] = vs[b];
      out[2 * b + 1] = vs[d];
    }
  } else if (i < 2 * tot) {
    int ii = i - tot;
    int r = ii / C, q = ii % C;
    if (q < cntg[KRANGES + r]) {
      int2 p = pairs1[ii];
      int er = E - 1 - p.y;
      int b = er_to_rank[er], d = noderank1[p.x];
      float* o1 = out + 2 * (size_t)m;
      o1[2 * b] = vs[b];
      o1[2 * b + 1] = vs[d];
    }
  } else if (i == 2 * tot) {
    // essential dim-0 class: eldest simplex (rank 0), death = fmax (rank m-1)
    out[0] = vs[0];
    out[1] = vs[m - 1];
  }
}

extern "C" void kernel_launch(void* const* d_in, const int* in_sizes, int n_in,
                              void* d_out, int out_size, void* d_ws, size_t ws_size,
                              hipStream_t stream) {
  const float* img = (const float*)d_in[0];
  const int* edges = (const int*)d_in[1];
  const int* tri_edges = (const int*)d_in[2];
  int N = in_sizes[0];
  int E = in_sizes[1] / 2;
  int F = in_sizes[2] / 3;
  int m = N + E + F;
  int C = (E + KRANGES - 1) / KRANGES;
  int NT = (m + TS - 1) / TS;
  int KB = (m + 1023) / 1024;
  float* out = (float*)d_out;

  char* p = (char*)d_ws;
  auto alloc = [&](size_t bytes) { char* r = p; p += (bytes + 255) & ~(size_t)255; return r; };
  u64* keys        = (u64*)alloc((size_t)m * 8);
  float* vals      = (float*)alloc((size_t)m * 4);
  float* vsorted   = (float*)alloc((size_t)m * 4);
  uint32_t* pack   = (uint32_t*)alloc((size_t)m * 4);
  int* vr_to_rank  = (int*)alloc((size_t)N * 4);
  int* er_to_rank  = (int*)alloc((size_t)E * 4);
  int* noderank1   = (int*)alloc((size_t)(F + 1) * 4);
  int* deg         = (int*)alloc((size_t)E * 4);
  int* adj         = (int*)alloc((size_t)E * 8);
  uint32_t* eAB0   = (uint32_t*)alloc((size_t)E * 4);
  uint32_t* eAB1   = (uint32_t*)alloc((size_t)E * 4);
  int2* pairs0     = (int2*)alloc((size_t)KRANGES * C * 8);
  int2* pairs1     = (int2*)alloc((size_t)KRANGES * C * 8);
  int* cntg        = (int*)alloc((size_t)2 * KRANGES * 4);
  (void)ws_size; (void)n_in;

  int out_n = out_size;
  int prep_n = out_n > m ? out_n : m;
  if (prep_n < 3 * F) prep_n = 3 * F;

  hipMemsetAsync(pack, 0, (size_t)m * 4, stream);
  hipMemsetAsync(deg, 0, (size_t)E * 4, stream);
  k_prep<<<(prep_n + 255) / 256, 256, 0, stream>>>(img, edges, tri_edges, vals, keys,
                                                   deg, adj, out, N, E, F, m, out_n);
  dim3 cg(NT, KB);
  k_count<<<cg, 256, 0, stream>>>(keys, pack, N, E, m);
  k_maps<<<(m + 255) / 256, 256, 0, stream>>>(pack, vals, edges, deg, adj,
                                              vsorted, vr_to_rank, er_to_rank, noderank1,
                                              eAB0, eAB1, N, E, F, m);
  k_pair<<<2 * KRANGES, 512, 0, stream>>>(eAB0, eAB1, pairs0, pairs1, cntg, N, E, F, C);
  k_emit<<<(2 * KRANGES * C + 1 + 255) / 256, 256, 0, stream>>>(pairs0, pairs1, cntg,
                                                                vr_to_rank, er_to_rank,
                                                                noderank1, vsorted, out,
                                                                E, C, m);
}

// Round 6
// 75.810 us; speedup vs baseline: 244.1044x; 2.5927x over previous
//
#include <hip/hip_runtime.h>
#include <stdint.h>

typedef unsigned long long u64;

// Problem-size caps (H=W=48 grid per reference).
#define NMAX 2304
#define EMAX 6721
#define FMAX 4418
#define KRANGES 128
#define CMAX 128
#define TS 512
#define KPB 512

// Monotone float -> uint32 mapping (IEEE total order for non-NaN).
static __device__ __forceinline__ uint32_t f2ord(float f) {
  uint32_t u = __float_as_uint(f);
  return (u & 0x80000000u) ? ~u : (u | 0x80000000u);
}

// Fused prep: zero output + pack, compute all simplex values directly from img,
// build sort keys, and fill edge->triangle adjacency (atomics; deg pre-zeroed).
__global__ void k_prep(const float* img, const int* edges, const int* tri_edges,
                       float* vals, u64* keys, uint32_t* pack, int* deg, int* adj,
                       float* out, int N, int E, int F, int m, int out_n) {
  int i = blockIdx.x * blockDim.x + threadIdx.x;
  if (i < out_n) out[i] = 0.0f;
  if (i < m) {
    pack[i] = 0u;
    float v;
    if (i < N) {
      v = img[i];
    } else if (i < N + E) {
      int e = i - N;
      v = fmaxf(img[edges[2 * e]], img[edges[2 * e + 1]]);
    } else {
      int t = i - N - E;
      float mx = -3.402823466e38f;
      #pragma unroll
      for (int k = 0; k < 3; ++k) {
        int e = tri_edges[3 * t + k];
        mx = fmaxf(mx, fmaxf(img[edges[2 * e]], img[edges[2 * e + 1]]));
      }
      v = mx;
    }
    vals[i] = v;
    keys[i] = ((u64)f2ord(v) << 32) | (u64)(uint32_t)i;
  }
  if (i < 3 * F) {
    int e = tri_edges[i];
    int t = i / 3;
    int slot = atomicAdd(&deg[e], 1);
    adj[2 * e + slot] = t;
  }
}

// Counting-rank: grid (tile, key-block), TS=512 tile in LDS, 2 keys/thread.
// Class counts come free by segmenting the tile at the N / N+E boundaries
// (classes are contiguous index ranges). One packed atomicAdd per (key, tile).
__global__ __launch_bounds__(256) void k_count(const u64* keys, uint32_t* pack,
                                               int N, int E, int m) {
  __shared__ __align__(16) u64 s[TS];
  int base = blockIdx.x * TS;
  int lim = min(TS, m - base);
  for (int j = threadIdx.x; j < lim; j += 256) s[j] = keys[base + j];
  __syncthreads();
  int ki0 = blockIdx.y * KPB + threadIdx.x;
  int ki1 = ki0 + 256;
  u64 k0 = (ki0 < m) ? keys[ki0] : ~0ull;
  u64 k1 = (ki1 < m) ? keys[ki1] : ~0ull;
  int cls0 = (ki0 < N) ? 0 : (ki0 < N + E ? 1 : 2);
  int cls1 = (ki1 < N) ? 0 : (ki1 < N + E ? 1 : 2);
  int sb1 = min(max(N - base, 0), lim);
  int sb2 = min(max(N + E - base, 0), lim);
  int segb[4] = {0, sb1, sb2, lim};
  int tot0 = 0, tot1 = 0, c0 = 0, c1 = 0;
  #pragma unroll
  for (int sg = 0; sg < 3; ++sg) {
    int lo = segb[sg], hh = segb[sg + 1];
    int t0 = 0, t1 = 0;
    int j = lo;
    if (j < hh && (j & 1)) {
      u64 e = s[j];
      t0 += (e < k0); t1 += (e < k1);
      ++j;
    }
    #pragma unroll 4
    for (; j + 1 < hh; j += 2) {
      u64 ex = s[j], ey = s[j + 1];
      t0 += (ex < k0) + (ey < k0);
      t1 += (ex < k1) + (ey < k1);
    }
    if (j < hh) {
      u64 e = s[j];
      t0 += (e < k0); t1 += (e < k1);
    }
    tot0 += t0; tot1 += t1;
    if (cls0 == sg) c0 += t0;
    if (cls1 == sg) c1 += t1;
  }
  if (ki0 < m) atomicAdd(&pack[ki0], ((uint32_t)c0 << 16) | (uint32_t)tot0);
  if (ki1 < m) atomicAdd(&pack[ki1], ((uint32_t)c1 << 16) | (uint32_t)tot1);
}

// Fused scatter+build: everything read straight out of pack[].
// eAB0[er] = primal endpoints as vranks; eAB1[E-1-er] = dual endpoints as node
// ids (node id = F - trank; outer face = 0; smaller = elder).
__global__ void k_maps(const uint32_t* pack, const float* vals, const int* edges,
                       const int* deg, const int* adj,
                       float* vsorted, int* vr_to_rank, int* er_to_rank, int* noderank1,
                       uint32_t* eAB0, uint32_t* eAB1,
                       int N, int E, int F, int m) {
  int i = blockIdx.x * blockDim.x + threadIdx.x;
  if (i >= m) return;
  uint32_t pk = pack[i];
  int rank = (int)(pk & 0xffffu);
  int cls = (int)(pk >> 16);
  vsorted[rank] = vals[i];
  if (i < N) {
    vr_to_rank[cls] = rank;
  } else if (i < N + E) {
    int e = i - N, er = cls;
    er_to_rank[er] = rank;
    uint32_t va = pack[edges[2 * e]] >> 16;
    uint32_t vb = pack[edges[2 * e + 1]] >> 16;
    eAB0[er] = (va << 16) | vb;
    uint32_t na = (uint32_t)F - (pack[N + E + adj[2 * e]] >> 16);
    uint32_t nb = (deg[e] == 2) ? ((uint32_t)F - (pack[N + E + adj[2 * e + 1]] >> 16)) : 0u;
    eAB1[E - 1 - er] = (na << 16) | nb;
  } else {
    noderank1[F - cls] = rank;
  }
}

// ECL-CC representative with inline path compression (benign races; final
// root of every component = its minimum node id — deterministic).
static __device__ __forceinline__ int rep(volatile int* par, int v) {
  int p = par[v];
  if (p == v) return v;
  int gp = par[p];
  while (p != gp) {
    par[v] = gp;
    v = p; p = gp; gp = par[p];
  }
  return p;
}

// Range-parallel elder-rule pairing + fused emit. Block (g, r): graph g
// (0 = primal/dim0, 1 = dual-reversed/dim1), edge range [P, P+C).
// Phase A: prefix-graph DSU via asynchronous min-hooking (each prefix edge
// processed ONCE) + full compression. Phase B: one thread runs the serial
// elder-rule UF over the range's edges into an LDS pair buffer. Phase C: all
// threads materialize the output floats for this block's pairs.
__global__ __launch_bounds__(512) void k_pair(const uint32_t* eAB0, const uint32_t* eAB1,
                                              const int* vr_to_rank, const int* er_to_rank,
                                              const int* noderank1, const float* vs,
                                              float* out, int N, int E, int F, int C, int m) {
  __shared__ int s_par[FMAX + 1];
  __shared__ uint32_t s_re[CMAX];
  __shared__ int2 s_pairs[CMAX];
  __shared__ int s_cnt;
  volatile int* vp = s_par;
  int tid = threadIdx.x;
  int g = blockIdx.x / KRANGES;
  int r = blockIdx.x % KRANGES;
  int NODES = (g == 0) ? N : (F + 1);
  const uint32_t* eAB = (g == 0) ? eAB0 : eAB1;
  int P = r * C;
  if (P >= E) return;
  int hi = min(P + C, E);
  for (int x = tid; x < NODES; x += 512) s_par[x] = x;
  for (int q = tid; q < hi - P; q += 512) s_re[q] = eAB[P + q];
  __syncthreads();
  // Phase A: async hooking over prefix edges [0, P)
  for (int i = tid; i < P; i += 512) {
    uint32_t ab = eAB[i];
    int a = (int)(ab >> 16), b = (int)(ab & 0xffffu);
    int u = rep(vp, a), w = rep(vp, b);
    while (u != w) {
      if (u < w) { int t = u; u = w; w = t; }
      int old = atomicCAS((int*)&s_par[u], u, w);
      if (old == u) break;
      u = rep(vp, old);
      w = rep(vp, w);
    }
  }
  __syncthreads();
  // Full compression: par[x] = root(x) (= component min)
  for (int x = tid; x < NODES; x += 512) {
    int r0 = x;
    while (vp[r0] != r0) r0 = vp[r0];
    s_par[x] = r0;
  }
  __syncthreads();
  // Phase B: serial elder-rule UF over range edges
  if (tid == 0) {
    int c = 0;
    for (int q = 0; q < hi - P; ++q) {
      uint32_t ab = s_re[q];
      int a = (int)(ab >> 16), b = (int)(ab & 0xffffu);
      int x = a;
      while (s_par[x] != x) { s_par[x] = s_par[s_par[x]]; x = s_par[x]; }
      int y = b;
      while (s_par[y] != y) { s_par[y] = s_par[s_par[y]]; y = s_par[y]; }
      if (x != y) {
        int die = x > y ? x : y, sur = x < y ? x : y;
        s_par[die] = sur;
        s_pairs[c++] = make_int2(die, P + q);
      }
    }
    s_cnt = c;
  }
  __syncthreads();
  // Phase C: parallel emit
  int c = s_cnt;
  if (g == 0) {
    for (int q = tid; q < c; q += 512) {
      int2 pq = s_pairs[q];
      int b = vr_to_rank[pq.x], d = er_to_rank[pq.y];
      out[2 * b] = vs[b];
      out[2 * b + 1] = vs[d];
    }
    if (r == 0 && tid == 0) {
      // essential dim-0 class: eldest simplex (rank 0), death = fmax (rank m-1)
      out[0] = vs[0];
      out[1] = vs[m - 1];
    }
  } else {
    float* o1 = out + 2 * (size_t)m;
    for (int q = tid; q < c; q += 512) {
      int2 pq = s_pairs[q];
      int er = E - 1 - pq.y;
      int b = er_to_rank[er], d = noderank1[pq.x];
      o1[2 * b] = vs[b];
      o1[2 * b + 1] = vs[d];
    }
  }
}

extern "C" void kernel_launch(void* const* d_in, const int* in_sizes, int n_in,
                              void* d_out, int out_size, void* d_ws, size_t ws_size,
                              hipStream_t stream) {
  const float* img = (const float*)d_in[0];
  const int* edges = (const int*)d_in[1];
  const int* tri_edges = (const int*)d_in[2];
  int N = in_sizes[0];
  int E = in_sizes[1] / 2;
  int F = in_sizes[2] / 3;
  int m = N + E + F;
  int C = (E + KRANGES - 1) / KRANGES;
  int NT = (m + TS - 1) / TS;
  int KB = (m + KPB - 1) / KPB;
  float* out = (float*)d_out;

  char* p = (char*)d_ws;
  auto alloc = [&](size_t bytes) { char* r = p; p += (bytes + 255) & ~(size_t)255; return r; };
  u64* keys        = (u64*)alloc((size_t)m * 8);
  float* vals      = (float*)alloc((size_t)m * 4);
  float* vsorted   = (float*)alloc((size_t)m * 4);
  uint32_t* pack   = (uint32_t*)alloc((size_t)m * 4);
  int* vr_to_rank  = (int*)alloc((size_t)N * 4);
  int* er_to_rank  = (int*)alloc((size_t)E * 4);
  int* noderank1   = (int*)alloc((size_t)(F + 1) * 4);
  int* deg         = (int*)alloc((size_t)E * 4);
  int* adj         = (int*)alloc((size_t)E * 8);
  uint32_t* eAB0   = (uint32_t*)alloc((size_t)E * 4);
  uint32_t* eAB1   = (uint32_t*)alloc((size_t)E * 4);
  (void)ws_size; (void)n_in;

  int out_n = out_size;
  int prep_n = out_n > m ? out_n : m;
  if (prep_n < 3 * F) prep_n = 3 * F;

  hipMemsetAsync(deg, 0, (size_t)E * 4, stream);
  k_prep<<<(prep_n + 255) / 256, 256, 0, stream>>>(img, edges, tri_edges, vals, keys,
                                                   pack, deg, adj, out, N, E, F, m, out_n);
  dim3 cg(NT, KB);
  k_count<<<cg, 256, 0, stream>>>(keys, pack, N, E, m);
  k_maps<<<(m + 255) / 256, 256, 0, stream>>>(pack, vals, edges, deg, adj,
                                              vsorted, vr_to_rank, er_to_rank, noderank1,
                                              eAB0, eAB1, N, E, F, m);
  k_pair<<<2 * KRANGES, 512, 0, stream>>>(eAB0, eAB1, vr_to_rank, er_to_rank,
                                          noderank1, vsorted, out, N, E, F, C, m);
}

// Round 7
// 60.149 us; speedup vs baseline: 307.6632x; 1.2604x over previous
//
#include <hip/hip_runtime.h>
#include <stdint.h>

typedef unsigned long long u64;

// Problem-size caps (H=W=48 grid per reference).
#define NMAX 2304
#define EMAX 6721
#define FMAX 4418
#define KRANGES 128
#define CMAX 64
#define TS 512
#define KPB 512

// Monotone float -> uint32 mapping (IEEE total order for non-NaN).
static __device__ __forceinline__ uint32_t f2ord(float f) {
  uint32_t u = __float_as_uint(f);
  return (u & 0x80000000u) ? ~u : (u | 0x80000000u);
}

// Fused prep: zero output + pack, compute all simplex values directly from img,
// build sort keys, and fill edge->triangle adjacency (atomics; deg pre-zeroed).
__global__ void k_prep(const float* img, const int* edges, const int* tri_edges,
                       float* vals, u64* keys, uint32_t* pack, int* deg, int* adj,
                       float* out, int N, int E, int F, int m, int out_n) {
  int i = blockIdx.x * blockDim.x + threadIdx.x;
  if (i < out_n) out[i] = 0.0f;
  if (i < m) {
    pack[i] = 0u;
    float v;
    if (i < N) {
      v = img[i];
    } else if (i < N + E) {
      int e = i - N;
      v = fmaxf(img[edges[2 * e]], img[edges[2 * e + 1]]);
    } else {
      int t = i - N - E;
      float mx = -3.402823466e38f;
      #pragma unroll
      for (int k = 0; k < 3; ++k) {
        int e = tri_edges[3 * t + k];
        mx = fmaxf(mx, fmaxf(img[edges[2 * e]], img[edges[2 * e + 1]]));
      }
      v = mx;
    }
    vals[i] = v;
    keys[i] = ((u64)f2ord(v) << 32) | (u64)(uint32_t)i;
  }
  if (i < 3 * F) {
    int e = tri_edges[i];
    int t = i / 3;
    int slot = atomicAdd(&deg[e], 1);
    adj[2 * e + slot] = t;
  }
}

// Counting-rank: grid (tile, key-block), TS=512 tile in LDS, 2 keys/thread.
// Class counts come free by segmenting the tile at the N / N+E boundaries
// (classes are contiguous index ranges). One packed atomicAdd per (key, tile).
__global__ __launch_bounds__(256) void k_count(const u64* keys, uint32_t* pack,
                                               int N, int E, int m) {
  __shared__ __align__(16) u64 s[TS];
  int base = blockIdx.x * TS;
  int lim = min(TS, m - base);
  for (int j = threadIdx.x; j < lim; j += 256) s[j] = keys[base + j];
  __syncthreads();
  int ki0 = blockIdx.y * KPB + threadIdx.x;
  int ki1 = ki0 + 256;
  u64 k0 = (ki0 < m) ? keys[ki0] : ~0ull;
  u64 k1 = (ki1 < m) ? keys[ki1] : ~0ull;
  int cls0 = (ki0 < N) ? 0 : (ki0 < N + E ? 1 : 2);
  int cls1 = (ki1 < N) ? 0 : (ki1 < N + E ? 1 : 2);
  int sb1 = min(max(N - base, 0), lim);
  int sb2 = min(max(N + E - base, 0), lim);
  int segb[4] = {0, sb1, sb2, lim};
  int tot0 = 0, tot1 = 0, c0 = 0, c1 = 0;
  #pragma unroll
  for (int sg = 0; sg < 3; ++sg) {
    int lo = segb[sg], hh = segb[sg + 1];
    int t0 = 0, t1 = 0;
    int j = lo;
    if (j < hh && (j & 1)) {
      u64 e = s[j];
      t0 += (e < k0); t1 += (e < k1);
      ++j;
    }
    #pragma unroll 4
    for (; j + 1 < hh; j += 2) {
      u64 ex = s[j], ey = s[j + 1];
      t0 += (ex < k0) + (ey < k0);
      t1 += (ex < k1) + (ey < k1);
    }
    if (j < hh) {
      u64 e = s[j];
      t0 += (e < k0); t1 += (e < k1);
    }
    tot0 += t0; tot1 += t1;
    if (cls0 == sg) c0 += t0;
    if (cls1 == sg) c1 += t1;
  }
  if (ki0 < m) atomicAdd(&pack[ki0], ((uint32_t)c0 << 16) | (uint32_t)tot0);
  if (ki1 < m) atomicAdd(&pack[ki1], ((uint32_t)c1 << 16) | (uint32_t)tot1);
}

// Fused scatter+build: everything read straight out of pack[].
// eAB0[er] = primal endpoints as vranks; eAB1[E-1-er] = dual endpoints as node
// ids (node id = F - trank; outer face = 0; smaller = elder).
__global__ void k_maps(const uint32_t* pack, const float* vals, const int* edges,
                       const int* deg, const int* adj,
                       float* vsorted, int* vr_to_rank, int* er_to_rank, int* noderank1,
                       uint32_t* eAB0, uint32_t* eAB1,
                       int N, int E, int F, int m) {
  int i = blockIdx.x * blockDim.x + threadIdx.x;
  if (i >= m) return;
  uint32_t pk = pack[i];
  int rank = (int)(pk & 0xffffu);
  int cls = (int)(pk >> 16);
  vsorted[rank] = vals[i];
  if (i < N) {
    vr_to_rank[cls] = rank;
  } else if (i < N + E) {
    int e = i - N, er = cls;
    er_to_rank[er] = rank;
    uint32_t va = pack[edges[2 * e]] >> 16;
    uint32_t vb = pack[edges[2 * e + 1]] >> 16;
    eAB0[er] = (va << 16) | vb;
    uint32_t na = (uint32_t)F - (pack[N + E + adj[2 * e]] >> 16);
    uint32_t nb = (deg[e] == 2) ? ((uint32_t)F - (pack[N + E + adj[2 * e + 1]] >> 16)) : 0u;
    eAB1[E - 1 - er] = (na << 16) | nb;
  } else {
    noderank1[F - cls] = rank;
  }
}

// ECL-CC representative with inline path compression (benign races; final
// root of every component = its minimum node id — deterministic).
static __device__ __forceinline__ int rep(volatile int* par, int v) {
  int p = par[v];
  if (p == v) return v;
  int gp = par[p];
  while (p != gp) {
    par[v] = gp;
    v = p; p = gp; gp = par[p];
  }
  return p;
}

// Range-parallel elder-rule pairing + fused emit. Block (g, r): graph g
// (0 = primal/dim0, 1 = dual-reversed/dim1), edge range [P, P+C).
// Phase A: prefix-graph DSU via asynchronous min-hooking, dual-chain root
// walks (both finds progress per iteration) + full compression.
// Phase B: parallel pre-resolve of range-edge roots, wave-0 ballot-compaction
// of merging candidates (order-preserving), short serial elder-rule UF.
// Phase C: all threads materialize the output floats.
__global__ __launch_bounds__(1024) void k_pair(const uint32_t* eAB0, const uint32_t* eAB1,
                                               const int* vr_to_rank, const int* er_to_rank,
                                               const int* noderank1, const float* vs,
                                               float* out, int N, int E, int F, int C, int m) {
  __shared__ int s_par[FMAX + 1];
  __shared__ uint32_t s_rr[CMAX];
  __shared__ int s_ci[CMAX];
  __shared__ int2 s_pairs[CMAX];
  __shared__ int s_cnt;
  volatile int* vp = s_par;
  int tid = threadIdx.x;
  int g = blockIdx.x / KRANGES;
  int r = blockIdx.x % KRANGES;
  int NODES = (g == 0) ? N : (F + 1);
  const uint32_t* eAB = (g == 0) ? eAB0 : eAB1;
  int P = r * C;
  if (P >= E) return;
  int hi = min(P + C, E);
  int nR = hi - P;
  for (int x = tid; x < NODES; x += 1024) s_par[x] = x;
  __syncthreads();
  // Phase A: async hooking over prefix edges [0, P), dual-chain walks
  for (int i = tid; i < P; i += 1024) {
    uint32_t ab = eAB[i];
    int va = (int)(ab >> 16), vb = (int)(ab & 0xffffu);
    int pa = vp[va], pb = vp[vb];
    int ga = vp[pa], gb = vp[pb];
    while (pa != ga || pb != gb) {
      if (pa != ga) { vp[va] = ga; va = pa; pa = ga; ga = vp[pa]; }
      if (pb != gb) { vp[vb] = gb; vb = pb; pb = gb; gb = vp[pb]; }
    }
    int u = pa, w = pb;
    while (u != w) {
      if (u < w) { int t = u; u = w; w = t; }
      int old = atomicCAS((int*)&s_par[u], u, w);
      if (old == u) break;
      u = rep(vp, old);
      w = rep(vp, w);
    }
  }
  __syncthreads();
  // Full compression: par[x] = root(x) (= component min)
  for (int x = tid; x < NODES; x += 1024) {
    int r0 = x;
    while (vp[r0] != r0) r0 = vp[r0];
    s_par[x] = r0;
  }
  __syncthreads();
  // Pre-resolve range-edge roots (exact after compression)
  for (int q = tid; q < nR; q += 1024) {
    uint32_t ab = eAB[P + q];
    int ra = s_par[ab >> 16];
    int rb = s_par[ab & 0xffffu];
    s_rr[q] = ((uint32_t)ra << 16) | (uint32_t)rb;
  }
  __syncthreads();
  // Wave-0: compact candidates (roots differ), then lane-0 serial UF
  if (tid < 64) {
    uint32_t rr = (tid < nR) ? s_rr[tid] : 0u;
    int keep = (tid < nR) && ((rr >> 16) != (rr & 0xffffu));
    u64 mask = __ballot(keep);
    if (keep) {
      int idx = __popcll(mask & ((1ull << tid) - 1ull));
      s_rr[idx] = rr;
      s_ci[idx] = tid;
    }
    int kc = __popcll(mask);
    if (tid == 0) {
      int c = 0;
      for (int i = 0; i < kc; ++i) {
        uint32_t rr2 = s_rr[i];
        int x = (int)(rr2 >> 16), y = (int)(rr2 & 0xffffu);
        while (s_par[x] != x) { s_par[x] = s_par[s_par[x]]; x = s_par[x]; }
        while (s_par[y] != y) { s_par[y] = s_par[s_par[y]]; y = s_par[y]; }
        if (x != y) {
          int die = x > y ? x : y, sur = x < y ? x : y;
          s_par[die] = sur;
          s_pairs[c++] = make_int2(die, P + s_ci[i]);
        }
      }
      s_cnt = c;
    }
  }
  __syncthreads();
  // Phase C: parallel emit
  int c = s_cnt;
  if (g == 0) {
    for (int q = tid; q < c; q += 1024) {
      int2 pq = s_pairs[q];
      int b = vr_to_rank[pq.x], d = er_to_rank[pq.y];
      out[2 * b] = vs[b];
      out[2 * b + 1] = vs[d];
    }
    if (r == 0 && tid == 0) {
      // essential dim-0 class: eldest simplex (rank 0), death = fmax (rank m-1)
      out[0] = vs[0];
      out[1] = vs[m - 1];
    }
  } else {
    float* o1 = out + 2 * (size_t)m;
    for (int q = tid; q < c; q += 1024) {
      int2 pq = s_pairs[q];
      int er = E - 1 - pq.y;
      int b = er_to_rank[er], d = noderank1[pq.x];
      o1[2 * b] = vs[b];
      o1[2 * b + 1] = vs[d];
    }
  }
}

extern "C" void kernel_launch(void* const* d_in, const int* in_sizes, int n_in,
                              void* d_out, int out_size, void* d_ws, size_t ws_size,
                              hipStream_t stream) {
  const float* img = (const float*)d_in[0];
  const int* edges = (const int*)d_in[1];
  const int* tri_edges = (const int*)d_in[2];
  int N = in_sizes[0];
  int E = in_sizes[1] / 2;
  int F = in_sizes[2] / 3;
  int m = N + E + F;
  int C = (E + KRANGES - 1) / KRANGES;
  int NT = (m + TS - 1) / TS;
  int KB = (m + KPB - 1) / KPB;
  float* out = (float*)d_out;

  char* p = (char*)d_ws;
  auto alloc = [&](size_t bytes) { char* r = p; p += (bytes + 255) & ~(size_t)255; return r; };
  u64* keys        = (u64*)alloc((size_t)m * 8);
  float* vals      = (float*)alloc((size_t)m * 4);
  float* vsorted   = (float*)alloc((size_t)m * 4);
  uint32_t* pack   = (uint32_t*)alloc((size_t)m * 4);
  int* vr_to_rank  = (int*)alloc((size_t)N * 4);
  int* er_to_rank  = (int*)alloc((size_t)E * 4);
  int* noderank1   = (int*)alloc((size_t)(F + 1) * 4);
  int* deg         = (int*)alloc((size_t)E * 4);
  int* adj         = (int*)alloc((size_t)E * 8);
  uint32_t* eAB0   = (uint32_t*)alloc((size_t)E * 4);
  uint32_t* eAB1   = (uint32_t*)alloc((size_t)E * 4);
  (void)ws_size; (void)n_in;

  int out_n = out_size;
  int prep_n = out_n > m ? out_n : m;
  if (prep_n < 3 * F) prep_n = 3 * F;

  hipMemsetAsync(deg, 0, (size_t)E * 4, stream);
  k_prep<<<(prep_n + 255) / 256, 256, 0, stream>>>(img, edges, tri_edges, vals, keys,
                                                   pack, deg, adj, out, N, E, F, m, out_n);
  dim3 cg(NT, KB);
  k_count<<<cg, 256, 0, stream>>>(keys, pack, N, E, m);
  k_maps<<<(m + 255) / 256, 256, 0, stream>>>(pack, vals, edges, deg, adj,
                                              vsorted, vr_to_rank, er_to_rank, noderank1,
                                              eAB0, eAB1, N, E, F, m);
  k_pair<<<2 * KRANGES, 1024, 0, stream>>>(eAB0, eAB1, vr_to_rank, er_to_rank,
                                           noderank1, vsorted, out, N, E, F, C, m);
}